// Round 2
// baseline (5119.918 us; speedup 1.0000x reference)
//
#include <hip/hip_runtime.h>

typedef short s16x8 __attribute__((ext_vector_type(8)));
typedef float f32x4 __attribute__((ext_vector_type(4)));
typedef _Float16 h2 __attribute__((ext_vector_type(2)));
typedef unsigned u32x4 __attribute__((ext_vector_type(4)));
typedef unsigned u32x2 __attribute__((ext_vector_type(2)));

static __device__ __forceinline__ unsigned short f2bf(float f){
  unsigned u = __builtin_bit_cast(unsigned, f);
  unsigned r = (u + 0x7fffu + ((u >> 16) & 1u)) >> 16;
  return (unsigned short)r;
}
static __device__ __forceinline__ float sigm(float x){
  return __builtin_amdgcn_rcpf(1.f + __expf(-x));
}
static __device__ __forceinline__ float tanh_(float x){
  float e = __expf(2.f * x);
  return 1.f - 2.f * __builtin_amdgcn_rcpf(e + 1.f);
}
static __device__ __forceinline__ unsigned pk2(float a, float b){
  h2 h = { (_Float16)a, (_Float16)b };
  return __builtin_bit_cast(unsigned, h);
}
static __device__ __forceinline__ h2 bch2(unsigned u){
  return __builtin_bit_cast(h2, u);
}
static __device__ __forceinline__ float dot2(unsigned x, unsigned w, float acc){
  return __builtin_amdgcn_fdot2(bch2(x), bch2(w), acc, false);
}

// ---------------- generic transpose: out[c*R + r] = in[r*ld + c] ----------------
__global__ void k_tr(const float* __restrict__ in, float* __restrict__ out, int R, int C, int ld){
  int i = blockIdx.x * 256 + threadIdx.x;
  if (i >= R * C) return;
  int c = i / R, r = i - c * R;
  out[i] = in[r * ld + c];
}

// ---------------- pack W_out into MFMA-B-fragment order, bf16 ----------------
__global__ void k_wbpack(const float* __restrict__ W, unsigned short* __restrict__ Wb){
  int p = blockIdx.x * 256 + threadIdx.x;   // 8,192,000 total
  int j = p & 7, l = (p >> 3) & 63, ks = (p >> 9) & 7, nt = p >> 12;
  int v = nt * 16 + (l & 15);
  int k = ks * 32 + ((l >> 4) << 3) + j;
  Wb[p] = f2bf(W[v * 256 + k]);
}

// ---------------- pack gate-weight family to f16 slices ----------------
// dst slice cs (24 cols): [kp 0..127][c 0..23][j 0..1], element = src[g*ld + k0 + k]
__global__ void k_packW(const float* __restrict__ src, unsigned short* __restrict__ dst,
                        int ld, int k0){
  int idx = blockIdx.x * 256 + threadIdx.x;   // 196608
  int g = idx >> 8, k = idx & 255;
  int cs = g / 24, c = g - cs * 24;
  _Float16 v = (_Float16)src[g * ld + k0 + k];
  dst[cs * 6144 + (k >> 1) * 48 + c * 2 + (k & 1)] = __builtin_bit_cast(unsigned short, v);
}

// Wa: per (l, cs) slice of 8 cols: [kp 0..127][c8 0..7][j]
__global__ void k_packWa(const float* __restrict__ Wa, unsigned short* __restrict__ dst){
  int idx = blockIdx.x * 256 + threadIdx.x;   // 262144
  int c = idx >> 10, kk = idx & 1023;
  int l = kk >> 8, k = kk & 255;
  int cs = c >> 3, c8 = c & 7;
  _Float16 v = (_Float16)Wa[c * 1024 + kk];
  dst[(l * 32 + cs) * 2048 + (k >> 1) * 16 + c8 * 2 + (k & 1)] = __builtin_bit_cast(unsigned short, v);
}

// ---------------- UaK[b,s,h] = keys[b,s,:] @ Ua.T + bUa ----------------
__global__ void k_uak(const float* __restrict__ keys, const float* __restrict__ UaT,
                      const float* __restrict__ bUa, float* __restrict__ UaK){
  __shared__ float kl[256];
  int row = blockIdx.x, tid = threadIdx.x;
  kl[tid] = keys[row * 256 + tid];
  __syncthreads();
  float acc = bUa[tid];
  #pragma unroll 8
  for (int k = 0; k < 256; ++k) acc += kl[k] * UaT[k * 256 + tid];
  UaK[row * 256 + tid] = acc;
}

// ---------------- giE[t,b,:] = emb(tok) @ W_ih0[:, :256].T + b_ih[0] ----------------
__global__ void k_gie(const int* __restrict__ tok, const float* __restrict__ emb,
                      const float* __restrict__ W0eT, const float* __restrict__ bih,
                      float* __restrict__ giE){
  __shared__ float el[256];
  int blk = blockIdx.x;                 // blk = t*32 + b
  int t = blk >> 5, b = blk & 31, tid = threadIdx.x;
  int tk = tok[b * 64 + t];
  el[tid] = emb[tk * 256 + tid];
  __syncthreads();
  for (int g = tid; g < 768; g += 256){
    float acc = bih[g];
    #pragma unroll 8
    for (int k = 0; k < 256; ++k) acc += el[k] * W0eT[k * 768 + g];
    giE[blk * 768 + g] = acc;
  }
}

// ---------------- grid barrier (32 co-resident blocks) ----------------
static __device__ __forceinline__ void gridbar(int* bar, int* epoch){
  __syncthreads();
  if (threadIdx.x == 0){
    ++(*epoch);
    __hip_atomic_fetch_add(bar, 1, __ATOMIC_ACQ_REL, __HIP_MEMORY_SCOPE_AGENT);
    const int target = 32 * (*epoch);
    while (__hip_atomic_load(bar, __ATOMIC_ACQUIRE, __HIP_MEMORY_SCOPE_AGENT) < target)
      __builtin_amdgcn_s_sleep(2);
  }
  __syncthreads();
}

// ---------------- cooperative recurrence: block = weight column-slice ----------------
__launch_bounds__(512, 1)
__global__ void k_rec(const float* __restrict__ keys, const float* __restrict__ ehid,
                      const unsigned short* __restrict__ WaP,
                      const unsigned short* __restrict__ WhhP,
                      const unsigned short* __restrict__ WihP,
                      const float* __restrict__ bWa, const float* __restrict__ Va,
                      const float* __restrict__ bVa,
                      const float* __restrict__ UaK, const float* __restrict__ giE,
                      const float* __restrict__ bih, const float* __restrict__ bhh,
                      float* __restrict__ qWgP, unsigned* __restrict__ ghgP,
                      unsigned* __restrict__ gigP, unsigned* __restrict__ ctx2g,
                      int* __restrict__ bar,
                      unsigned short* __restrict__ Xb, float* __restrict__ outH,
                      float* __restrict__ outA)
{
  __shared__ unsigned Hpk[32][4][132];   // packed f16 h pairs, all batches/layers
  __shared__ unsigned Cpk[32][128];      // packed ctx
  __shared__ float vlds[256];
  __shared__ float qWl[256];
  __shared__ float sc[64], watt[64];
  __shared__ float ctxl[256];
  __shared__ float red[512];
  const int cs = blockIdx.x;             // column-slice id == attn batch id
  const int tid = threadIdx.x;

  for (int i = tid; i < 16384; i += 512){
    int l = i >> 12, b = (i >> 7) & 31, kp = i & 127;
    const float* hp = ehid + l * 8192 + b * 256 + 2 * kp;
    Hpk[b][l][kp] = pk2(hp[0], hp[1]);
  }
  if (tid < 256) vlds[tid] = Va[tid];
  __syncthreads();

  int epoch = 0;
  for (int t = 0; t < 64; ++t){
    const int tp = t & 1;
    // ---- Phase A: qW per-layer partials + gh (all layers), K=256 f16 dot2 ----
    #pragma unroll
    for (int pass = 0; pass < 2; ++pass){
      const int u = pass * 512 + tid;
      const int b = u >> 5, m = u & 31;
      float a0, a1, a2, a3;
      const unsigned short* wb;
      int l, c0, wstep;
      if (m < 8){
        l = m >> 1; const int cg = m & 1;
        wb = WaP + (l * 32 + cs) * 2048 + cg * 8;
        wstep = 16; c0 = cs * 8 + cg * 4;
        a0 = a1 = a2 = a3 = 0.f;
      } else {
        const int mm = m - 8; l = mm / 6; const int cg = mm - l * 6;
        wb = WhhP + (l * 32 + cs) * 6144 + cg * 8;
        wstep = 48; c0 = cs * 24 + cg * 4;
        const float4 bb = *(const float4*)(bhh + l * 768 + c0);
        a0 = bb.x; a1 = bb.y; a2 = bb.z; a3 = bb.w;
      }
      const unsigned* xp = &Hpk[b][l][0];
      #pragma unroll 8
      for (int kp = 0; kp < 128; ++kp){
        u32x4 w = *(const u32x4*)(wb + kp * wstep);
        unsigned x = xp[kp];
        a0 = dot2(x, w.x, a0); a1 = dot2(x, w.y, a1);
        a2 = dot2(x, w.z, a2); a3 = dot2(x, w.w, a3);
      }
      if (m < 8){
        *(f32x4*)(qWgP + (b * 4 + l) * 256 + c0) = (f32x4){a0, a1, a2, a3};
      } else {
        u32x2 o = { pk2(a0, a1), pk2(a2, a3) };
        *(u32x2*)(ghgP + tp * 49152 + (l * 32 + b) * 384 + (c0 >> 1)) = o;
      }
    }
    gridbar(bar, &epoch);

    // ---- attention for batch cs ----
    if (tid < 256){
      qWl[tid] = qWgP[(cs * 4 + 0) * 256 + tid] + qWgP[(cs * 4 + 1) * 256 + tid]
               + qWgP[(cs * 4 + 2) * 256 + tid] + qWgP[(cs * 4 + 3) * 256 + tid] + bWa[tid];
    }
    __syncthreads();
    {
      int s = tid >> 3, p = tid & 7;
      const float* up = UaK + ((cs << 6) + s) * 256 + p * 32;
      const float* qp = qWl + p * 32;
      const float* vp = vlds + p * 32;
      float acc = 0.f;
      #pragma unroll 8
      for (int i = 0; i < 32; ++i) acc += vp[i] * tanh_(qp[i] + up[i]);
      acc += __shfl_xor(acc, 1, 64);
      acc += __shfl_xor(acc, 2, 64);
      acc += __shfl_xor(acc, 4, 64);
      if (p == 0) sc[s] = acc + bVa[0];
    }
    __syncthreads();
    if (tid < 64){
      float v = sc[tid];
      float m2 = v;
      #pragma unroll
      for (int off = 1; off < 64; off <<= 1) m2 = fmaxf(m2, __shfl_xor(m2, off, 64));
      float e = __expf(v - m2);
      float ssum = e;
      #pragma unroll
      for (int off = 1; off < 64; off <<= 1) ssum += __shfl_xor(ssum, off, 64);
      float w = e * __builtin_amdgcn_rcpf(ssum);
      watt[tid] = w;
      outA[(cs * 64 + t) * 64 + tid] = w;
    }
    __syncthreads();
    {
      int o = tid & 255, p = tid >> 8;
      const float* kp2 = keys + (cs * 64 + p * 32) * 256 + o;
      float acc = 0.f;
      #pragma unroll 8
      for (int s2 = 0; s2 < 32; ++s2) acc += watt[p * 32 + s2] * kp2[s2 * 256];
      red[tid] = acc;
    }
    __syncthreads();
    if (tid < 256) ctxl[tid] = red[tid] + red[256 + tid];
    __syncthreads();
    if (tid < 128) ctx2g[cs * 128 + tid] = pk2(ctxl[2 * tid], ctxl[2 * tid + 1]);
    gridbar(bar, &epoch);

    // stage all batches' ctx
    for (int i = tid; i < 4096; i += 512) Cpk[i >> 7][i & 127] = ctx2g[i];
    __syncthreads();

    // ---- GRU layers ----
    const int tb = t * 32;
    for (int l = 0; l < 4; ++l){
      if (tid < 192){
        const int b = tid / 6, cg = tid - b * 6;
        const int c0 = cs * 24 + cg * 4;
        const unsigned short* wb = WihP + (l * 32 + cs) * 6144 + cg * 8;
        float a0, a1, a2, a3;
        if (l == 0){
          const float4 bb = *(const float4*)(giE + (tb + b) * 768 + c0);
          a0 = bb.x; a1 = bb.y; a2 = bb.z; a3 = bb.w;
        } else {
          const float4 bb = *(const float4*)(bih + l * 768 + c0);
          a0 = bb.x; a1 = bb.y; a2 = bb.z; a3 = bb.w;
        }
        const unsigned* xp = (l == 0) ? &Cpk[b][0] : &Hpk[b][l - 1][0];
        #pragma unroll 8
        for (int kp = 0; kp < 128; ++kp){
          u32x4 w = *(const u32x4*)(wb + kp * 48);
          unsigned x = xp[kp];
          a0 = dot2(x, w.x, a0); a1 = dot2(x, w.y, a1);
          a2 = dot2(x, w.z, a2); a3 = dot2(x, w.w, a3);
        }
        u32x2 o = { pk2(a0, a1), pk2(a2, a3) };
        *(u32x2*)(gigP + l * 12288 + b * 384 + (c0 >> 1)) = o;
      }
      gridbar(bar, &epoch);
      // gates: redundant in every block; updates local Hpk[.][l]
      const unsigned* gl = gigP + l * 12288;
      const unsigned* gh = ghgP + tp * 49152 + l * 32 * 384;
      #pragma unroll
      for (int i2 = 0; i2 < 8; ++i2){
        const int u = tid + i2 * 512;
        const int b = u >> 7, kp = u & 127;
        h2 gir = bch2(gl[b * 384 + kp]);
        h2 giz = bch2(gl[b * 384 + 128 + kp]);
        h2 gin = bch2(gl[b * 384 + 256 + kp]);
        h2 ghr = bch2(gh[b * 384 + kp]);
        h2 ghz = bch2(gh[b * 384 + 128 + kp]);
        h2 ghn = bch2(gh[b * 384 + 256 + kp]);
        h2 hp = bch2(Hpk[b][l][kp]);
        float hn0, hn1;
        {
          float r = sigm((float)gir[0] + (float)ghr[0]);
          float z = sigm((float)giz[0] + (float)ghz[0]);
          float n = tanh_((float)gin[0] + r * (float)ghn[0]);
          hn0 = (1.f - z) * n + z * (float)hp[0];
        }
        {
          float r = sigm((float)gir[1] + (float)ghr[1]);
          float z = sigm((float)giz[1] + (float)ghz[1]);
          float n = tanh_((float)gin[1] + r * (float)ghn[1]);
          hn1 = (1.f - z) * n + z * (float)hp[1];
        }
        Hpk[b][l][kp] = pk2(hn0, hn1);
        if (l == 3 && b == cs)
          *(unsigned*)(Xb + (cs * 64 + t) * 256 + 2 * kp) =
              (unsigned)f2bf(hn0) | ((unsigned)f2bf(hn1) << 16);
        if (t == 63 && b == cs){
          outH[l * 8192 + cs * 256 + 2 * kp]     = hn0;
          outH[l * 8192 + cs * 256 + 2 * kp + 1] = hn1;
        }
      }
      __syncthreads();
    }
  }
}

// ---------------- logits pass 1: per-row sum(exp(logit)) partials ----------------
__launch_bounds__(512)
__global__ void k_g1(const unsigned short* __restrict__ Xb, const unsigned short* __restrict__ Wb,
                     const float* __restrict__ bout, float* __restrict__ Spart)
{
  const int mt = blockIdx.x, nc = blockIdx.y;
  const int tid = threadIdx.x, lane = tid & 63, wv = tid >> 6;
  const int c = lane & 15, q = lane >> 4;
  const int r0 = mt * 64;
  s16x8 afr[4][8];
  #pragma unroll
  for (int rt = 0; rt < 4; ++rt){
    const unsigned short* xp = Xb + (r0 + rt * 16 + c) * 256 + q * 8;
    #pragma unroll
    for (int ks = 0; ks < 8; ++ks) afr[rt][ks] = *(const s16x8*)(xp + ks * 32);
  }
  float ssum[4][4];
  #pragma unroll
  for (int rt = 0; rt < 4; ++rt){ ssum[rt][0]=0.f; ssum[rt][1]=0.f; ssum[rt][2]=0.f; ssum[rt][3]=0.f; }
  const int ntEnd = nc * 250 + 250;
  for (int nt = nc * 250 + wv; nt < ntEnd; nt += 8){
    const unsigned short* wp = Wb + nt * 4096 + lane * 8;
    f32x4 acc[4];
    #pragma unroll
    for (int rt = 0; rt < 4; ++rt) acc[rt] = (f32x4){0.f, 0.f, 0.f, 0.f};
    #pragma unroll
    for (int ks = 0; ks < 8; ++ks){
      s16x8 bfr = *(const s16x8*)(wp + ks * 512);
      #pragma unroll
      for (int rt = 0; rt < 4; ++rt)
        acc[rt] = __builtin_amdgcn_mfma_f32_16x16x32_bf16(afr[rt][ks], bfr, acc[rt], 0, 0, 0);
    }
    float bo = bout[nt * 16 + c];
    #pragma unroll
    for (int rt = 0; rt < 4; ++rt){
      #pragma unroll
      for (int i = 0; i < 4; ++i) ssum[rt][i] += __expf(acc[rt][i] + bo);
    }
  }
  #pragma unroll
  for (int off = 1; off < 16; off <<= 1){
    #pragma unroll
    for (int rt = 0; rt < 4; ++rt){
      #pragma unroll
      for (int i = 0; i < 4; ++i) ssum[rt][i] += __shfl_xor(ssum[rt][i], off, 64);
    }
  }
  __shared__ float lred[8][64];
  if (c == 0){
    #pragma unroll
    for (int rt = 0; rt < 4; ++rt){
      #pragma unroll
      for (int i = 0; i < 4; ++i) lred[wv][rt * 16 + q * 4 + i] = ssum[rt][i];
    }
  }
  __syncthreads();
  if (tid < 64){
    float s = 0.f;
    #pragma unroll
    for (int w = 0; w < 8; ++w) s += lred[w][tid];
    Spart[(r0 + tid) * 8 + nc] = s;
  }
}

__global__ void k_g1b(const float* __restrict__ Spart, float* __restrict__ Z){
  int r = blockIdx.x * 256 + threadIdx.x;
  float s = 0.f;
  #pragma unroll
  for (int nc = 0; nc < 8; ++nc) s += Spart[r * 8 + nc];
  Z[r] = __logf(s);
}

// ---------------- logits pass 2: recompute, write log_softmax ----------------
__launch_bounds__(512)
__global__ void k_g2(const unsigned short* __restrict__ Xb, const unsigned short* __restrict__ Wb,
                     const float* __restrict__ bout, const float* __restrict__ Z,
                     float* __restrict__ out)
{
  const int mt = blockIdx.x, nc = blockIdx.y;
  const int tid = threadIdx.x, lane = tid & 63, wv = tid >> 6;
  const int c = lane & 15, q = lane >> 4;
  const int r0 = mt * 64;
  s16x8 afr[4][8];
  #pragma unroll
  for (int rt = 0; rt < 4; ++rt){
    const unsigned short* xp = Xb + (r0 + rt * 16 + c) * 256 + q * 8;
    #pragma unroll
    for (int ks = 0; ks < 8; ++ks) afr[rt][ks] = *(const s16x8*)(xp + ks * 32);
  }
  float zr[4][4];
  #pragma unroll
  for (int rt = 0; rt < 4; ++rt){
    #pragma unroll
    for (int i = 0; i < 4; ++i) zr[rt][i] = Z[r0 + rt * 16 + q * 4 + i];
  }
  const int ntEnd = nc * 250 + 250;
  for (int nt = nc * 250 + wv; nt < ntEnd; nt += 8){
    const unsigned short* wp = Wb + nt * 4096 + lane * 8;
    f32x4 acc[4];
    #pragma unroll
    for (int rt = 0; rt < 4; ++rt) acc[rt] = (f32x4){0.f, 0.f, 0.f, 0.f};
    #pragma unroll
    for (int ks = 0; ks < 8; ++ks){
      s16x8 bfr = *(const s16x8*)(wp + ks * 512);
      #pragma unroll
      for (int rt = 0; rt < 4; ++rt)
        acc[rt] = __builtin_amdgcn_mfma_f32_16x16x32_bf16(afr[rt][ks], bfr, acc[rt], 0, 0, 0);
    }
    float bo = bout[nt * 16 + c];
    #pragma unroll
    for (int rt = 0; rt < 4; ++rt){
      #pragma unroll
      for (int i = 0; i < 4; ++i)
        out[(r0 + rt * 16 + q * 4 + i) * 32000 + nt * 16 + c] = acc[rt][i] + bo - zr[rt][i];
    }
  }
}

extern "C" void kernel_launch(void* const* d_in, const int* in_sizes, int n_in,
                              void* d_out, int out_size, void* d_ws, size_t ws_size,
                              hipStream_t stream)
{
  const float* keys = (const float*)d_in[0];
  const float* ehid = (const float*)d_in[1];
  const int*   dinp = (const int*)d_in[2];
  const float* emb  = (const float*)d_in[3];
  const float* Wa   = (const float*)d_in[4];
  const float* bWa  = (const float*)d_in[5];
  const float* Ua   = (const float*)d_in[6];
  const float* bUa  = (const float*)d_in[7];
  const float* Va   = (const float*)d_in[8];
  const float* bVa  = (const float*)d_in[9];
  const float* Wih0 = (const float*)d_in[10];
  const float* Wihr = (const float*)d_in[11];
  const float* Whh  = (const float*)d_in[12];
  const float* bih  = (const float*)d_in[13];
  const float* bhh  = (const float*)d_in[14];
  const float* Wout = (const float*)d_in[15];
  const float* bout = (const float*)d_in[16];

  char* p = (char*)d_ws;
  auto alloc = [&](size_t n){ char* r = p; p += (n + 255) & ~(size_t)255; return r; };
  unsigned short* WaP  = (unsigned short*)alloc(262144 * 2);
  unsigned short* WhhP = (unsigned short*)alloc(786432 * 2);
  unsigned short* WihP = (unsigned short*)alloc(786432 * 2);
  float* UaT   = (float*)alloc(65536 * 4);
  float* W0eT  = (float*)alloc(196608 * 4);
  float* UaK   = (float*)alloc(524288 * 4);
  float* giE   = (float*)alloc(1572864 * 4);
  unsigned short* Xb = (unsigned short*)alloc(524288 * 2);
  unsigned short* Wb = (unsigned short*)alloc(8192000 * 2);
  float* Spart = (float*)alloc(16384 * 4);
  float* Zr    = (float*)alloc(2048 * 4);
  float* qWgP  = (float*)alloc(32768 * 4);
  unsigned* ghgP = (unsigned*)alloc(98304 * 4);
  unsigned* gigP = (unsigned*)alloc(49152 * 4);
  unsigned* ctx2g = (unsigned*)alloc(4096 * 4);
  int* bar = (int*)alloc(256);

  float* outL = (float*)d_out;
  float* outH = outL + 65536000;
  float* outA = outH + 32768;

  // transposes still needed for UaK / giE precompute
  k_tr<<<256, 256, 0, stream>>>(Ua,   UaT,  256, 256, 256);
  k_tr<<<768, 256, 0, stream>>>(Wih0, W0eT, 768, 256, 512);

  // f16 slice packs
  k_packWa<<<1024, 256, 0, stream>>>(Wa, WaP);
  for (int l = 0; l < 4; ++l)
    k_packW<<<768, 256, 0, stream>>>(Whh + l * 196608, WhhP + l * 196608, 256, 0);
  k_packW<<<768, 256, 0, stream>>>(Wih0, WihP, 512, 256);
  for (int l = 1; l < 4; ++l)
    k_packW<<<768, 256, 0, stream>>>(Wihr + (l - 1) * 196608, WihP + l * 196608, 256, 0);

  k_wbpack<<<32000, 256, 0, stream>>>(Wout, Wb);
  k_uak<<<2048, 256, 0, stream>>>(keys, UaT, bUa, UaK);
  k_gie<<<2048, 256, 0, stream>>>(dinp, emb, W0eT, bih, giE);

  hipMemsetAsync(bar, 0, 256, stream);

  k_rec<<<32, 512, 0, stream>>>(keys, ehid, WaP, WhhP, WihP, bWa, Va, bVa,
                                UaK, giE, bih, bhh,
                                qWgP, ghgP, gigP, ctx2g, bar, Xb, outH, outA);

  k_g1<<<dim3(32, 8), 512, 0, stream>>>(Xb, Wb, bout, Spart);
  k_g1b<<<8, 256, 0, stream>>>(Spart, Zr);
  k_g2<<<dim3(32, 8), 512, 0, stream>>>(Xb, Wb, bout, Zr, outL);
}

// Round 3
// 4690.443 us; speedup vs baseline: 1.0916x; 1.0916x over previous
//
#include <hip/hip_runtime.h>

typedef short s16x8 __attribute__((ext_vector_type(8)));
typedef _Float16 f16x8 __attribute__((ext_vector_type(8)));
typedef float f32x4 __attribute__((ext_vector_type(4)));

static __device__ __forceinline__ unsigned short f2bf(float f){
  unsigned u = __builtin_bit_cast(unsigned, f);
  unsigned r = (u + 0x7fffu + ((u >> 16) & 1u)) >> 16;
  return (unsigned short)r;
}
static __device__ __forceinline__ float sigm(float x){
  return __builtin_amdgcn_rcpf(1.f + __expf(-x));
}
static __device__ __forceinline__ float tanh_(float x){
  float e = __expf(2.f * x);
  return 1.f - 2.f * __builtin_amdgcn_rcpf(e + 1.f);
}

// ---------------- generic transpose: out[c*R + r] = in[r*ld + c] ----------------
__global__ void k_tr(const float* __restrict__ in, float* __restrict__ out, int R, int C, int ld){
  int i = blockIdx.x * 256 + threadIdx.x;
  if (i >= R * C) return;
  int c = i / R, r = i - c * R;
  out[i] = in[r * ld + c];
}

// ---------------- pack W_out into MFMA-B-fragment order, bf16 (for logits) ----------------
__global__ void k_wbpack(const float* __restrict__ W, unsigned short* __restrict__ Wb){
  int p = blockIdx.x * 256 + threadIdx.x;   // 8,192,000 total
  int j = p & 7, l = (p >> 3) & 63, ks = (p >> 9) & 7, nt = p >> 12;
  int v = nt * 16 + (l & 15);
  int k = ks * 32 + ((l >> 4) << 3) + j;
  Wb[p] = f2bf(W[v * 256 + k]);
}

// ---------------- pack Whh into f16 MFMA-B fragment order ----------------
// flat = ((tile*8+ks)*64+lane)*8+j ; tile = l*48+nt ; B[n][k]: n=lane&15, k=ks*32+(lane>>4)*8+j
__global__ void k_wpackA(const float* __restrict__ Whh, _Float16* __restrict__ dst){
  int p = blockIdx.x * 256 + threadIdx.x;   // 786432
  int j = p & 7, lane = (p >> 3) & 63, ks = (p >> 9) & 7, tile = p >> 12;
  int l = tile / 48, nt = tile - l * 48;
  int row = nt * 16 + (lane & 15);
  int k = ks * 32 + ((lane >> 4) << 3) + j;
  dst[p] = (_Float16)Whh[l * 196608 + row * 256 + k];
}

// ---------------- pack Wa (qW) : tile = kc*16+nt, row = out col of qW ----------------
__global__ void k_wpackQ(const float* __restrict__ Wa, _Float16* __restrict__ dst){
  int p = blockIdx.x * 256 + threadIdx.x;   // 262144
  int j = p & 7, lane = (p >> 3) & 63, ks = (p >> 9) & 7, tile = p >> 12;
  int kc = tile >> 4, nt = tile & 15;
  int row = nt * 16 + (lane & 15);
  int k = ks * 32 + ((lane >> 4) << 3) + j;
  dst[p] = (_Float16)Wa[row * 1024 + kc * 256 + k];
}

// ---------------- pack Wih (gi) : tile = l*48+nt ----------------
__global__ void k_wpackI(const float* __restrict__ Wih0, const float* __restrict__ Wihr,
                         _Float16* __restrict__ dst){
  int p = blockIdx.x * 256 + threadIdx.x;   // 786432
  int j = p & 7, lane = (p >> 3) & 63, ks = (p >> 9) & 7, tile = p >> 12;
  int l = tile / 48, nt = tile - l * 48;
  int row = nt * 16 + (lane & 15);
  int k = ks * 32 + ((lane >> 4) << 3) + j;
  float v = (l == 0) ? Wih0[row * 512 + 256 + k]
                     : Wihr[(l - 1) * 196608 + row * 256 + k];
  dst[p] = (_Float16)v;
}

// ---------------- UaK[b,s,h] = keys[b,s,:] @ Ua.T + bUa ----------------
__global__ void k_uak(const float* __restrict__ keys, const float* __restrict__ UaT,
                      const float* __restrict__ bUa, float* __restrict__ UaK){
  __shared__ float kl[256];
  int row = blockIdx.x, tid = threadIdx.x;
  kl[tid] = keys[row * 256 + tid];
  __syncthreads();
  float acc = bUa[tid];
  #pragma unroll 8
  for (int k = 0; k < 256; ++k) acc += kl[k] * UaT[k * 256 + tid];
  UaK[row * 256 + tid] = acc;
}

// ---------------- giE[t,b,:] = emb(tok) @ W_ih0[:, :256].T + b_ih[0] ----------------
__global__ void k_gie(const int* __restrict__ tok, const float* __restrict__ emb,
                      const float* __restrict__ W0eT, const float* __restrict__ bih,
                      float* __restrict__ giE){
  __shared__ float el[256];
  int blk = blockIdx.x;                 // blk = t*32 + b
  int t = blk >> 5, b = blk & 31, tid = threadIdx.x;
  int tk = tok[b * 64 + t];
  el[tid] = emb[tk * 256 + tid];
  __syncthreads();
  for (int g = tid; g < 768; g += 256){
    float acc = bih[g];
    #pragma unroll 8
    for (int k = 0; k < 256; ++k) acc += el[k] * W0eT[k * 768 + g];
    giE[blk * 768 + g] = acc;
  }
}

// ---------------- grid barrier (32 co-resident blocks) ----------------
static __device__ __forceinline__ void gridbar(int* bar, int* epoch){
  __syncthreads();
  if (threadIdx.x == 0){
    ++(*epoch);
    __hip_atomic_fetch_add(bar, 1, __ATOMIC_ACQ_REL, __HIP_MEMORY_SCOPE_AGENT);
    const int target = 32 * (*epoch);
    while (__hip_atomic_load(bar, __ATOMIC_ACQUIRE, __HIP_MEMORY_SCOPE_AGENT) < target)
      __builtin_amdgcn_s_sleep(1);
  }
  __syncthreads();
}

// ---------------- cooperative MFMA recurrence ----------------
// Groups: G_l = blocks [8l, 8l+8). G_l owns h_l (LDS, f16), computes gh_l + qW(kc=l)
// in phase A, gates_l (redundant 8-way), gi_{l+1} (gi_0 done by G_3 from ctx).
__launch_bounds__(512, 1)
__global__ void k_rec(const float* __restrict__ keys, const float* __restrict__ ehid,
                      const _Float16* __restrict__ WpkA, const _Float16* __restrict__ WpkQ,
                      const _Float16* __restrict__ WpkI,
                      const float* __restrict__ bWa, const float* __restrict__ Va,
                      const float* __restrict__ bVa,
                      const float* __restrict__ UaK, const float* __restrict__ giE,
                      const float* __restrict__ bih, const float* __restrict__ bhh,
                      float* __restrict__ qWg, _Float16* __restrict__ ghg,
                      _Float16* __restrict__ gig, _Float16* __restrict__ ctxg,
                      int* __restrict__ bar,
                      unsigned short* __restrict__ Xb, float* __restrict__ outH,
                      float* __restrict__ outA)
{
  __shared__ _Float16 hl[32][264];      // h of layer gl, padded (+8) for LDS banks
  __shared__ float vlds[256], bWal[256];
  __shared__ float bihl[768], bhhl[768];
  __shared__ float qWl[256];
  __shared__ float sc[64], watt[64];
  __shared__ float ctxl[256];
  __shared__ float red[512];

  const int cs = blockIdx.x, tid = threadIdx.x;
  const int gl = cs >> 3;         // group layer
  const int gidx = cs & 7;        // index within group
  const int wv = tid >> 6, lane = tid & 63;
  const int fc = lane & 15, fq = lane >> 4;

  // stage h_gl (f32 -> f16)
  for (int i = tid; i < 8192; i += 512){
    int b = i >> 8, k = i & 255;
    hl[b][k] = (_Float16)ehid[gl * 8192 + b * 256 + k];
  }
  if (tid < 256){ vlds[tid] = Va[tid]; bWal[tid] = bWa[tid]; }
  for (int i = tid; i < 768; i += 512){
    bihl[i] = bih[gl * 768 + i];
    bhhl[i] = bhh[gl * 768 + i];
  }
  __syncthreads();

  int epoch = 0;
  for (int t = 0; t < 64; ++t){

    // ===== w1: phase A — per wave one (M=32,N=16,K=256) unit =====
    {
      f16x8 afr0[8], afr1[8];
      #pragma unroll
      for (int ks = 0; ks < 8; ++ks){
        afr0[ks] = *(const f16x8*)&hl[fc][ks * 32 + fq * 8];
        afr1[ks] = *(const f16x8*)&hl[16 + fc][ks * 32 + fq * 8];
      }
      const _Float16* bp = (wv < 6)
          ? (WpkA + (gl * 48 + gidx * 6 + wv) * 4096)
          : (WpkQ + (gl * 16 + gidx * 2 + (wv - 6)) * 4096);
      f32x4 ac0 = {0.f,0.f,0.f,0.f}, ac1 = {0.f,0.f,0.f,0.f};
      #pragma unroll
      for (int ks = 0; ks < 8; ++ks){
        f16x8 bfr = *(const f16x8*)(bp + ks * 512 + lane * 8);
        ac0 = __builtin_amdgcn_mfma_f32_16x16x32_f16(afr0[ks], bfr, ac0, 0, 0, 0);
        ac1 = __builtin_amdgcn_mfma_f32_16x16x32_f16(afr1[ks], bfr, ac1, 0, 0, 0);
      }
      if (wv < 6){
        const int c0 = (gidx * 6 + wv) * 16 + fc;
        _Float16* dst = ghg + (gl * 32) * 768 + c0;
        #pragma unroll
        for (int i = 0; i < 4; ++i){
          dst[(fq * 4 + i) * 768]        = (_Float16)ac0[i];
          dst[(16 + fq * 4 + i) * 768]   = (_Float16)ac1[i];
        }
      } else {
        const int c0 = (gidx * 2 + (wv - 6)) * 16 + fc;
        float* dst = qWg + (gl * 32) * 256 + c0;
        #pragma unroll
        for (int i = 0; i < 4; ++i){
          dst[(fq * 4 + i) * 256]        = ac0[i];
          dst[(16 + fq * 4 + i) * 256]   = ac1[i];
        }
      }
    }
    gridbar(bar, &epoch);

    // ===== w2: attention for batch cs =====
    if (tid < 256){
      qWl[tid] = qWg[(0 * 32 + cs) * 256 + tid] + qWg[(1 * 32 + cs) * 256 + tid]
               + qWg[(2 * 32 + cs) * 256 + tid] + qWg[(3 * 32 + cs) * 256 + tid]
               + bWal[tid];
    }
    __syncthreads();
    {
      int s = tid >> 3, p = tid & 7;
      const float* up = UaK + ((cs << 6) + s) * 256 + p * 32;
      const float* qp = qWl + p * 32;
      const float* vp = vlds + p * 32;
      float acc = 0.f;
      #pragma unroll 8
      for (int i = 0; i < 32; ++i) acc += vp[i] * tanh_(qp[i] + up[i]);
      acc += __shfl_xor(acc, 1, 64);
      acc += __shfl_xor(acc, 2, 64);
      acc += __shfl_xor(acc, 4, 64);
      if (p == 0) sc[s] = acc + bVa[0];
    }
    __syncthreads();
    if (tid < 64){
      float v = sc[tid];
      float m2 = v;
      #pragma unroll
      for (int off = 1; off < 64; off <<= 1) m2 = fmaxf(m2, __shfl_xor(m2, off, 64));
      float e = __expf(v - m2);
      float ssum = e;
      #pragma unroll
      for (int off = 1; off < 64; off <<= 1) ssum += __shfl_xor(ssum, off, 64);
      float w = e * __builtin_amdgcn_rcpf(ssum);
      watt[tid] = w;
      outA[(cs * 64 + t) * 64 + tid] = w;
    }
    __syncthreads();
    {
      int o = tid & 255, p = tid >> 8;
      const float* kp2 = keys + (cs * 64 + p * 32) * 256 + o;
      float acc = 0.f;
      #pragma unroll 8
      for (int s2 = 0; s2 < 32; ++s2) acc += watt[p * 32 + s2] * kp2[s2 * 256];
      red[tid] = acc;
    }
    __syncthreads();
    if (tid < 256){
      ctxl[tid] = red[tid] + red[256 + tid];
      ctxg[cs * 256 + tid] = (_Float16)ctxl[tid];
    }
    gridbar(bar, &epoch);

    // gi helper: layer l, A from hl (xg==nullptr) or global f16 [32][256]
    auto do_gi = [&](int l, const _Float16* xg){
      f16x8 afr0[8], afr1[8];
      #pragma unroll
      for (int ks = 0; ks < 8; ++ks){
        if (xg){
          afr0[ks] = *(const f16x8*)(xg + fc * 256 + ks * 32 + fq * 8);
          afr1[ks] = *(const f16x8*)(xg + (16 + fc) * 256 + ks * 32 + fq * 8);
        } else {
          afr0[ks] = *(const f16x8*)&hl[fc][ks * 32 + fq * 8];
          afr1[ks] = *(const f16x8*)&hl[16 + fc][ks * 32 + fq * 8];
        }
      }
      const _Float16* bp = WpkI + (l * 48 + gidx * 6 + wv) * 4096;
      f32x4 ac0 = {0.f,0.f,0.f,0.f}, ac1 = {0.f,0.f,0.f,0.f};
      #pragma unroll
      for (int ks = 0; ks < 8; ++ks){
        f16x8 bfr = *(const f16x8*)(bp + ks * 512 + lane * 8);
        ac0 = __builtin_amdgcn_mfma_f32_16x16x32_f16(afr0[ks], bfr, ac0, 0, 0, 0);
        ac1 = __builtin_amdgcn_mfma_f32_16x16x32_f16(afr1[ks], bfr, ac1, 0, 0, 0);
      }
      const int c0 = (gidx * 6 + wv) * 16 + fc;
      _Float16* dst = gig + l * 24576 + c0;
      #pragma unroll
      for (int i = 0; i < 4; ++i){
        dst[(fq * 4 + i) * 768]      = (_Float16)ac0[i];
        dst[(16 + fq * 4 + i) * 768] = (_Float16)ac1[i];
      }
    };

    // gates helper for layer l == gl (updates hl in place)
    auto do_gates = [&](int l){
      const int b = tid >> 4, kq = (tid & 15) << 4;
      const _Float16* gp = gig + l * 24576 + b * 768 + kq;
      const _Float16* hp = ghg + (l * 32 + b) * 768 + kq;
      const float* gep = giE + (t * 32 + b) * 768 + kq;
      f16x8 gr0 = *(const f16x8*)(gp);       f16x8 gr1 = *(const f16x8*)(gp + 8);
      f16x8 gz0 = *(const f16x8*)(gp + 256); f16x8 gz1 = *(const f16x8*)(gp + 264);
      f16x8 gn0 = *(const f16x8*)(gp + 512); f16x8 gn1 = *(const f16x8*)(gp + 520);
      f16x8 hr0 = *(const f16x8*)(hp);       f16x8 hr1 = *(const f16x8*)(hp + 8);
      f16x8 hz0 = *(const f16x8*)(hp + 256); f16x8 hz1 = *(const f16x8*)(hp + 264);
      f16x8 hn0 = *(const f16x8*)(hp + 512); f16x8 hn1 = *(const f16x8*)(hp + 520);
      f16x8 ho0 = *(const f16x8*)&hl[b][kq];
      f16x8 ho1 = *(const f16x8*)&hl[b][kq + 8];
      f16x8 o0, o1;
      const bool mine = ((b >> 2) == gidx);
      #pragma unroll
      for (int i = 0; i < 8; ++i){
        {
          float giR = (float)gr0[i] + (l == 0 ? gep[i]       : bihl[kq + i]);
          float giZ = (float)gz0[i] + (l == 0 ? gep[256 + i] : bihl[256 + kq + i]);
          float giN = (float)gn0[i] + (l == 0 ? gep[512 + i] : bihl[512 + kq + i]);
          float r = sigm(giR + (float)hr0[i] + bhhl[kq + i]);
          float z = sigm(giZ + (float)hz0[i] + bhhl[256 + kq + i]);
          float n = tanh_(giN + r * ((float)hn0[i] + bhhl[512 + kq + i]));
          float hv = (1.f - z) * n + z * (float)ho0[i];
          o0[i] = (_Float16)hv;
          if (l == 3 && mine) Xb[(b * 64 + t) * 256 + kq + i] = f2bf(hv);
          if (t == 63 && mine) outH[l * 8192 + b * 256 + kq + i] = hv;
        }
        {
          float giR = (float)gr1[i] + (l == 0 ? gep[8 + i]       : bihl[kq + 8 + i]);
          float giZ = (float)gz1[i] + (l == 0 ? gep[264 + i]     : bihl[256 + kq + 8 + i]);
          float giN = (float)gn1[i] + (l == 0 ? gep[520 + i]     : bihl[512 + kq + 8 + i]);
          float r = sigm(giR + (float)hr1[i] + bhhl[kq + 8 + i]);
          float z = sigm(giZ + (float)hz1[i] + bhhl[256 + kq + 8 + i]);
          float n = tanh_(giN + r * ((float)hn1[i] + bhhl[512 + kq + 8 + i]));
          float hv = (1.f - z) * n + z * (float)ho1[i];
          o1[i] = (_Float16)hv;
          if (l == 3 && mine) Xb[(b * 64 + t) * 256 + kq + 8 + i] = f2bf(hv);
          if (t == 63 && mine) outH[l * 8192 + b * 256 + kq + 8 + i] = hv;
        }
      }
      *(f16x8*)&hl[b][kq] = o0;
      *(f16x8*)&hl[b][kq + 8] = o1;
    };

    // ===== w3: G_3 computes gi_0 from ctx =====
    if (gl == 3 && wv < 6) do_gi(0, ctxg);
    gridbar(bar, &epoch);

    // ===== w4..w6: G_lw: gates_lw then gi_{lw+1} =====
    for (int lw = 0; lw < 3; ++lw){
      if (gl == lw){
        do_gates(lw);
        __syncthreads();
        if (wv < 6) do_gi(lw + 1, nullptr);
      }
      gridbar(bar, &epoch);
    }

    // ===== w7: G_3: gates_3 (+ Xb, outH) — no barrier, flows into next phase A =====
    if (gl == 3) do_gates(3);
    __syncthreads();
  }
}

// ---------------- logits pass 1: per-row sum(exp(logit)) partials ----------------
__launch_bounds__(512)
__global__ void k_g1(const unsigned short* __restrict__ Xb, const unsigned short* __restrict__ Wb,
                     const float* __restrict__ bout, float* __restrict__ Spart)
{
  const int mt = blockIdx.x, nc = blockIdx.y;
  const int tid = threadIdx.x, lane = tid & 63, wvv = tid >> 6;
  const int c = lane & 15, q = lane >> 4;
  const int r0 = mt * 64;
  s16x8 afr[4][8];
  #pragma unroll
  for (int rt = 0; rt < 4; ++rt){
    const unsigned short* xp = Xb + (r0 + rt * 16 + c) * 256 + q * 8;
    #pragma unroll
    for (int ks = 0; ks < 8; ++ks) afr[rt][ks] = *(const s16x8*)(xp + ks * 32);
  }
  float ssum[4][4];
  #pragma unroll
  for (int rt = 0; rt < 4; ++rt){ ssum[rt][0]=0.f; ssum[rt][1]=0.f; ssum[rt][2]=0.f; ssum[rt][3]=0.f; }
  const int ntEnd = nc * 250 + 250;
  for (int nt = nc * 250 + wvv; nt < ntEnd; nt += 8){
    const unsigned short* wp = Wb + nt * 4096 + lane * 8;
    f32x4 acc[4];
    #pragma unroll
    for (int rt = 0; rt < 4; ++rt) acc[rt] = (f32x4){0.f, 0.f, 0.f, 0.f};
    #pragma unroll
    for (int ks = 0; ks < 8; ++ks){
      s16x8 bfr = *(const s16x8*)(wp + ks * 512);
      #pragma unroll
      for (int rt = 0; rt < 4; ++rt)
        acc[rt] = __builtin_amdgcn_mfma_f32_16x16x32_bf16(afr[rt][ks], bfr, acc[rt], 0, 0, 0);
    }
    float bo = bout[nt * 16 + c];
    #pragma unroll
    for (int rt = 0; rt < 4; ++rt){
      #pragma unroll
      for (int i = 0; i < 4; ++i) ssum[rt][i] += __expf(acc[rt][i] + bo);
    }
  }
  #pragma unroll
  for (int off = 1; off < 16; off <<= 1){
    #pragma unroll
    for (int rt = 0; rt < 4; ++rt){
      #pragma unroll
      for (int i = 0; i < 4; ++i) ssum[rt][i] += __shfl_xor(ssum[rt][i], off, 64);
    }
  }
  __shared__ float lred[8][64];
  if (c == 0){
    #pragma unroll
    for (int rt = 0; rt < 4; ++rt){
      #pragma unroll
      for (int i = 0; i < 4; ++i) lred[wvv][rt * 16 + q * 4 + i] = ssum[rt][i];
    }
  }
  __syncthreads();
  if (tid < 64){
    float s = 0.f;
    #pragma unroll
    for (int w = 0; w < 8; ++w) s += lred[w][tid];
    Spart[(r0 + tid) * 8 + nc] = s;
  }
}

__global__ void k_g1b(const float* __restrict__ Spart, float* __restrict__ Z){
  int r = blockIdx.x * 256 + threadIdx.x;
  float s = 0.f;
  #pragma unroll
  for (int nc = 0; nc < 8; ++nc) s += Spart[r * 8 + nc];
  Z[r] = __logf(s);
}

// ---------------- logits pass 2: recompute, write log_softmax ----------------
__launch_bounds__(512)
__global__ void k_g2(const unsigned short* __restrict__ Xb, const unsigned short* __restrict__ Wb,
                     const float* __restrict__ bout, const float* __restrict__ Z,
                     float* __restrict__ out)
{
  const int mt = blockIdx.x, nc = blockIdx.y;
  const int tid = threadIdx.x, lane = tid & 63, wvv = tid >> 6;
  const int c = lane & 15, q = lane >> 4;
  const int r0 = mt * 64;
  s16x8 afr[4][8];
  #pragma unroll
  for (int rt = 0; rt < 4; ++rt){
    const unsigned short* xp = Xb + (r0 + rt * 16 + c) * 256 + q * 8;
    #pragma unroll
    for (int ks = 0; ks < 8; ++ks) afr[rt][ks] = *(const s16x8*)(xp + ks * 32);
  }
  float zr[4][4];
  #pragma unroll
  for (int rt = 0; rt < 4; ++rt){
    #pragma unroll
    for (int i = 0; i < 4; ++i) zr[rt][i] = Z[r0 + rt * 16 + q * 4 + i];
  }
  const int ntEnd = nc * 250 + 250;
  for (int nt = nc * 250 + wvv; nt < ntEnd; nt += 8){
    const unsigned short* wp = Wb + nt * 4096 + lane * 8;
    f32x4 acc[4];
    #pragma unroll
    for (int rt = 0; rt < 4; ++rt) acc[rt] = (f32x4){0.f, 0.f, 0.f, 0.f};
    #pragma unroll
    for (int ks = 0; ks < 8; ++ks){
      s16x8 bfr = *(const s16x8*)(wp + ks * 512);
      #pragma unroll
      for (int rt = 0; rt < 4; ++rt)
        acc[rt] = __builtin_amdgcn_mfma_f32_16x16x32_bf16(afr[rt][ks], bfr, acc[rt], 0, 0, 0);
    }
    float bo = bout[nt * 16 + c];
    #pragma unroll
    for (int rt = 0; rt < 4; ++rt){
      #pragma unroll
      for (int i = 0; i < 4; ++i)
        out[(r0 + rt * 16 + q * 4 + i) * 32000 + nt * 16 + c] = acc[rt][i] + bo - zr[rt][i];
    }
  }
}

extern "C" void kernel_launch(void* const* d_in, const int* in_sizes, int n_in,
                              void* d_out, int out_size, void* d_ws, size_t ws_size,
                              hipStream_t stream)
{
  const float* keys = (const float*)d_in[0];
  const float* ehid = (const float*)d_in[1];
  const int*   dinp = (const int*)d_in[2];
  const float* emb  = (const float*)d_in[3];
  const float* Wa   = (const float*)d_in[4];
  const float* bWa  = (const float*)d_in[5];
  const float* Ua   = (const float*)d_in[6];
  const float* bUa  = (const float*)d_in[7];
  const float* Va   = (const float*)d_in[8];
  const float* bVa  = (const float*)d_in[9];
  const float* Wih0 = (const float*)d_in[10];
  const float* Wihr = (const float*)d_in[11];
  const float* Whh  = (const float*)d_in[12];
  const float* bih  = (const float*)d_in[13];
  const float* bhh  = (const float*)d_in[14];
  const float* Wout = (const float*)d_in[15];
  const float* bout = (const float*)d_in[16];

  char* p = (char*)d_ws;
  auto alloc = [&](size_t n){ char* r = p; p += (n + 255) & ~(size_t)255; return r; };
  _Float16* WpkA = (_Float16*)alloc(786432 * 2);
  _Float16* WpkQ = (_Float16*)alloc(262144 * 2);
  _Float16* WpkI = (_Float16*)alloc(786432 * 2);
  float* UaT   = (float*)alloc(65536 * 4);
  float* W0eT  = (float*)alloc(196608 * 4);
  float* UaK   = (float*)alloc(524288 * 4);
  float* giE   = (float*)alloc(1572864 * 4);
  unsigned short* Xb = (unsigned short*)alloc(524288 * 2);
  unsigned short* Wb = (unsigned short*)alloc(8192000 * 2);
  float* Spart = (float*)alloc(16384 * 4);
  float* Zr    = (float*)alloc(2048 * 4);
  float* qWg   = (float*)alloc(32768 * 4);
  _Float16* ghg = (_Float16*)alloc(98304 * 2);
  _Float16* gig = (_Float16*)alloc(98304 * 2);
  _Float16* ctxg = (_Float16*)alloc(8192 * 2);
  int* bar = (int*)alloc(256);

  float* outL = (float*)d_out;
  float* outH = outL + 65536000;
  float* outA = outH + 32768;

  // precompute transposes for UaK / giE
  k_tr<<<256, 256, 0, stream>>>(Ua,   UaT,  256, 256, 256);
  k_tr<<<768, 256, 0, stream>>>(Wih0, W0eT, 768, 256, 512);

  // fragment-order weight packs (f16)
  k_wpackA<<<3072, 256, 0, stream>>>(Whh, WpkA);
  k_wpackQ<<<1024, 256, 0, stream>>>(Wa, WpkQ);
  k_wpackI<<<3072, 256, 0, stream>>>(Wih0, Wihr, WpkI);

  k_wbpack<<<32000, 256, 0, stream>>>(Wout, Wb);
  k_uak<<<2048, 256, 0, stream>>>(keys, UaT, bUa, UaK);
  k_gie<<<2048, 256, 0, stream>>>(dinp, emb, W0eT, bih, giE);

  hipMemsetAsync(bar, 0, 256, stream);

  k_rec<<<32, 512, 0, stream>>>(keys, ehid, WpkA, WpkQ, WpkI, bWa, Va, bVa,
                                UaK, giE, bih, bhh,
                                qWg, ghg, gig, ctxg, bar, Xb, outH, outA);

  k_g1<<<dim3(32, 8), 512, 0, stream>>>(Xb, Wb, bout, Spart);
  k_g1b<<<8, 256, 0, stream>>>(Spart, Zr);
  k_g2<<<dim3(32, 8), 512, 0, stream>>>(Xb, Wb, bout, Zr, outL);
}